// Round 1
// baseline (699.908 us; speedup 1.0000x reference)
//
#include <hip/hip_runtime.h>

#define B 8
#define N 100000
#define NE 3200000
#define CHUNK_LOG 10
#define CHUNK 1024            // nodes per chunk (LDS acc = 8*1032*4 = 33 KB)
#define CSTRIDE 1032          // padded batch stride: 1032%32==8 -> atomics of one
                              // record hit 8 distinct banks; lanes spread all 32
#define NCHUNK 98             // ceil(N / CHUNK)
#define CAP 70000             // per-bucket capacity (expect ~65.5k +- 0.26k)
#define SEG 8                 // phase-2 blocks per chunk
#define EPB 4096              // phase-1 edges per block

struct Rec { int me; int other; float c; };   // 12 B endpoint record

// Static device scratch (graph-capture safe; recomputed fully every call).
__device__ Rec   g_rec[(size_t)NCHUNK * CAP];                    // 82.3 MB
__device__ int   g_cursor[NCHUNK];
__device__ float g_heads_t[N * B];                               // node-major heads
__device__ float g_partial[(size_t)NCHUNK * SEG * CHUNK * B];    // 25.7 MB
__device__ float g_accum;

// ---------------------------------------------------------------------------
__global__ __launch_bounds__(128) void zero_kernel() {
    int i = threadIdx.x;
    if (i < NCHUNK) g_cursor[i] = 0;
    if (i == 0) g_accum = 0.0f;
}

// heads (B,N) -> heads_t (N,B): each node's 8 batch values contiguous (32 B).
__global__ __launch_bounds__(256) void transpose_kernel(
    const float* __restrict__ node_heads)
{
    int i = blockIdx.x * blockDim.x + threadIdx.x;   // i = n*8 + b
    if (i >= N * B) return;
    int n = i >> 3, b = i & 7;
    g_heads_t[i] = node_heads[b * N + n];
}

// ---------------------------------------------------------------------------
// Phase 1: flows output + bucket endpoint records by node chunk.
// Contribution to node `me` is c*(h[me]-h[other]) for BOTH endpoints
// (src: +f = c*(h_s-h_d); dst: -f = c*(h_d-h_s)) -> uniform record.
// ---------------------------------------------------------------------------
__global__ __launch_bounds__(256) void phase1_kernel(
    const int* __restrict__ edge_index,     // (2, E) int32
    const float* __restrict__ edge_attr,    // (E, 2)
    float* __restrict__ flows_out)          // (B, E)
{
    __shared__ int s_s[EPB];
    __shared__ int s_d[EPB];
    __shared__ int hist[NCHUNK];
    int tid = threadIdx.x;
    int e0 = blockIdx.x * EPB;

    for (int i = tid; i < NCHUNK; i += 256) hist[i] = 0;
    __syncthreads();

    // pass A: block histogram of endpoint chunks; stage indices in LDS
#pragma unroll
    for (int i = 0; i < EPB / 256; ++i) {
        int idx = i * 256 + tid;
        int e = e0 + idx;
        int s = -1, d = -1;
        if (e < NE) {
            s = edge_index[e];
            d = edge_index[NE + e];
            atomicAdd(&hist[s >> CHUNK_LOG], 1);
            atomicAdd(&hist[d >> CHUNK_LOG], 1);
        }
        s_s[idx] = s;
        s_d[idx] = d;
    }
    __syncthreads();

    // reserve per-bucket space: ~NCHUNK global atomics per block
    for (int i = tid; i < NCHUNK; i += 256)
        hist[i] = atomicAdd(&g_cursor[i], hist[i]);   // hist -> running cursor
    __syncthreads();

    // pass B: compute flows, emit records
#pragma unroll
    for (int i = 0; i < EPB / 256; ++i) {
        int idx = i * 256 + tid;
        int e = e0 + idx;
        if (e >= NE) continue;
        int s = s_s[idx];
        int d = s_d[idx];
        float c = ((const float2*)edge_attr)[e].x;

        const float4* hs4 = (const float4*)&g_heads_t[s << 3];
        const float4* hd4 = (const float4*)&g_heads_t[d << 3];
        float4 a0 = hs4[0], a1 = hs4[1];
        float4 b0 = hd4[0], b1 = hd4[1];
        flows_out[0 * NE + e] = c * (a0.x - b0.x);
        flows_out[1 * NE + e] = c * (a0.y - b0.y);
        flows_out[2 * NE + e] = c * (a0.z - b0.z);
        flows_out[3 * NE + e] = c * (a0.w - b0.w);
        flows_out[4 * NE + e] = c * (a1.x - b1.x);
        flows_out[5 * NE + e] = c * (a1.y - b1.y);
        flows_out[6 * NE + e] = c * (a1.z - b1.z);
        flows_out[7 * NE + e] = c * (a1.w - b1.w);

        int ks = s >> CHUNK_LOG;
        int ps = atomicAdd(&hist[ks], 1);
        if (ps < CAP) { Rec r; r.me = s; r.other = d; r.c = c;
                        g_rec[(size_t)ks * CAP + ps] = r; }
        int kd = d >> CHUNK_LOG;
        int pd = atomicAdd(&hist[kd], 1);
        if (pd < CAP) { Rec r; r.me = d; r.other = s; r.c = c;
                        g_rec[(size_t)kd * CAP + pd] = r; }
    }
}

// ---------------------------------------------------------------------------
// Phase 2: per (chunk, segment) block LDS-accumulate records -> partials.
// SoA accumulator acc[b*CSTRIDE + node_local]: per-instruction bank index is
// (8*b + nl) & 31 -> 64 lanes spread over all 32 banks (~2-way, free per m136)
// instead of the old AoS layout's 4-bank 16-way pileup.
// ---------------------------------------------------------------------------
#define ACC8(R, A0, A1, O0, O1) do {                                   \
    int _ml = (R).me & (CHUNK - 1);                                    \
    atomicAdd(&acc[0 * CSTRIDE + _ml], (R).c * ((A0).x - (O0).x));     \
    atomicAdd(&acc[1 * CSTRIDE + _ml], (R).c * ((A0).y - (O0).y));     \
    atomicAdd(&acc[2 * CSTRIDE + _ml], (R).c * ((A0).z - (O0).z));     \
    atomicAdd(&acc[3 * CSTRIDE + _ml], (R).c * ((A0).w - (O0).w));     \
    atomicAdd(&acc[4 * CSTRIDE + _ml], (R).c * ((A1).x - (O1).x));     \
    atomicAdd(&acc[5 * CSTRIDE + _ml], (R).c * ((A1).y - (O1).y));     \
    atomicAdd(&acc[6 * CSTRIDE + _ml], (R).c * ((A1).z - (O1).z));     \
    atomicAdd(&acc[7 * CSTRIDE + _ml], (R).c * ((A1).w - (O1).w));     \
} while (0)

__global__ __launch_bounds__(256) void phase2_kernel() {
    __shared__ float acc[B * CSTRIDE];    // 33,024 B -> 4 blocks/CU resident
    int chunk = blockIdx.x / SEG;
    int seg   = blockIdx.x % SEG;

    for (int i = threadIdx.x; i < B * CSTRIDE; i += 256) acc[i] = 0.0f;
    __syncthreads();

    int cnt = g_cursor[chunk];
    if (cnt > CAP) cnt = CAP;
    size_t rbase = (size_t)chunk * CAP;

    const int STR = SEG * 256;
    int r = seg * 256 + threadIdx.x;
    // 2x unroll: two independent rec->heads load chains in flight per thread
    for (; r + STR < cnt; r += 2 * STR) {
        Rec r0 = g_rec[rbase + r];
        Rec r1 = g_rec[rbase + r + STR];
        const float4* m0 = (const float4*)&g_heads_t[r0.me << 3];
        const float4* o0 = (const float4*)&g_heads_t[r0.other << 3];
        const float4* m1 = (const float4*)&g_heads_t[r1.me << 3];
        const float4* o1 = (const float4*)&g_heads_t[r1.other << 3];
        float4 ma0 = m0[0], ma1 = m0[1];
        float4 oa0 = o0[0], oa1 = o0[1];
        float4 mb0 = m1[0], mb1 = m1[1];
        float4 ob0 = o1[0], ob1 = o1[1];
        ACC8(r0, ma0, ma1, oa0, oa1);
        ACC8(r1, mb0, mb1, ob0, ob1);
    }
    if (r < cnt) {
        Rec r0 = g_rec[rbase + r];
        const float4* m0 = (const float4*)&g_heads_t[r0.me << 3];
        const float4* o0 = (const float4*)&g_heads_t[r0.other << 3];
        float4 ma0 = m0[0], ma1 = m0[1];
        float4 oa0 = o0[0], oa1 = o0[1];
        ACC8(r0, ma0, ma1, oa0, oa1);
    }
    __syncthreads();

    // partial layout per block: [b][nl] (un-padded)
    float* out = &g_partial[(size_t)blockIdx.x * (CHUNK * B)];
    for (int i = threadIdx.x; i < CHUNK * B; i += 256) {
        int b  = i >> CHUNK_LOG;
        int nl = i & (CHUNK - 1);
        out[i] = acc[b * CSTRIDE + nl];
    }
}

// ---------------------------------------------------------------------------
// Merge partials + fused continuity reduction (no net buffer needed).
// idx iterates b-major (matches demands layout); partial reads coalesced in nl.
// ---------------------------------------------------------------------------
__global__ __launch_bounds__(256) void merge_cont_kernel(
    const float* __restrict__ demands)
{
    __shared__ float ssum[4];
    float local = 0.0f;
    int stride = gridDim.x * blockDim.x;
    for (int idx = blockIdx.x * blockDim.x + threadIdx.x; idx < N * B; idx += stride) {
        int b = idx / N;                  // 0..7 (magic-mul, cheap)
        int n = idx - b * N;
        int chunk = n >> CHUNK_LOG;
        int nl = n & (CHUNK - 1);
        size_t base = ((size_t)(chunk * SEG) * B + b) * CHUNK + nl;
        float v = 0.0f;
#pragma unroll
        for (int s = 0; s < SEG; ++s)
            v += g_partial[base + (size_t)s * (B * CHUNK)];
        v -= demands[idx];
        local = fmaf(v, v, local);
    }
    for (int off = 32; off > 0; off >>= 1)
        local += __shfl_down(local, off, 64);
    int lane = threadIdx.x & 63, wave = threadIdx.x >> 6;
    if (lane == 0) ssum[wave] = local;
    __syncthreads();
    if (threadIdx.x == 0)
        unsafeAtomicAdd(&g_accum, ssum[0] + ssum[1] + ssum[2] + ssum[3]);
}

// ---------------------------------------------------------------------------
// Boundary loss + finalize scalars.
// ---------------------------------------------------------------------------
__global__ __launch_bounds__(512) void finalize_kernel(
    const float* __restrict__ node_heads,
    const int* __restrict__ res_nodes,      // (64,) int32
    const float* __restrict__ res_head,     // (1,)
    float* __restrict__ out)
{
    __shared__ float ssum[8];
    int t = threadIdx.x;          // 512 = B*64
    int b = t >> 6;
    int j = t & 63;
    float pred = node_heads[b * N + res_nodes[j]];
    float diff = pred - res_head[0];
    float local = diff * diff;
    for (int off = 32; off > 0; off >>= 1)
        local += __shfl_down(local, off, 64);
    if ((t & 63) == 0) ssum[t >> 6] = local;
    __syncthreads();
    if (t == 0) {
        float bsum = 0.0f;
        for (int w = 0; w < 8; ++w) bsum += ssum[w];
        float boundary = bsum / 512.0f;
        float continuity = g_accum / (float)(B * N);
        out[0] = continuity;
        out[1] = boundary;
        out[2] = continuity + boundary;     // LAMBDA_PHYSICS = 1.0
    }
}

extern "C" void kernel_launch(void* const* d_in, const int* in_sizes, int n_in,
                              void* d_out, int out_size, void* d_ws, size_t ws_size,
                              hipStream_t stream) {
    const float* node_heads = (const float*)d_in[0];
    const float* demands    = (const float*)d_in[1];
    const int*   edge_index = (const int*)d_in[2];    // int32 per harness
    const float* edge_attr  = (const float*)d_in[3];
    const int*   res_nodes  = (const int*)d_in[4];    // int32 per harness
    const float* res_head   = (const float*)d_in[5];

    float* out = (float*)d_out;   // [cont, bound, total, flows(B,E)]

    zero_kernel<<<1, 128, 0, stream>>>();
    transpose_kernel<<<(N * B + 255) / 256, 256, 0, stream>>>(node_heads);
    phase1_kernel<<<(NE + EPB - 1) / EPB, 256, 0, stream>>>(
        edge_index, edge_attr, out + 3);
    phase2_kernel<<<NCHUNK * SEG, 256, 0, stream>>>();
    merge_cont_kernel<<<1024, 256, 0, stream>>>(demands);
    finalize_kernel<<<1, 512, 0, stream>>>(node_heads, res_nodes, res_head, out);
}